// Round 7
// baseline (499.546 us; speedup 1.0000x reference)
//
#include <hip/hip_runtime.h>

#define B_ 1024
#define M_ 64
#define N_ 8192
#define NSG 16   // k-splits for k_G  (chunk 1024 of K=16384)
#define NS3 8    // n-slabs for k_H23 (1024 cols each)

typedef __attribute__((ext_vector_type(8))) short bf16x8;
typedef __attribute__((ext_vector_type(4))) float f32x4;

__device__ inline unsigned short f2b(float f) {
    union { float f; unsigned u; } v; v.f = f;
    unsigned r = v.u + 0x7FFFu + ((v.u >> 16) & 1u);
    return (unsigned short)(r >> 16);
}
__device__ inline unsigned rne2(float lo, float hi) {
    union { float f; unsigned u; } a, b; a.f = lo; b.f = hi;
    unsigned x = (a.u + 0x7FFFu + ((a.u >> 16) & 1u)) >> 16;
    unsigned y = (b.u + 0x7FFFu + ((b.u >> 16) & 1u)) >> 16;
    return x | (y << 16);
}
// readlane: broadcast of lane l's value (l compile-time under full unroll)
__device__ inline float rl(float v, int l) {
    return __builtin_bit_cast(float, __builtin_amdgcn_readlane(__builtin_bit_cast(int, v), l));
}

// ---------------------------------------------------------------------------
// zero the imaginary rows of out-x: out[(2b+1)*N + n] = 0
__global__ __launch_bounds__(256) void k_zero_imag(float* out) {
    int b = blockIdx.y;
    int n = (blockIdx.x * 256 + threadIdx.x) * 4;
    float4 z = make_float4(0.f, 0.f, 0.f, 0.f);
    *(float4*)(out + (size_t)(2 * b + 1) * N_ + n) = z;
}

// ---------------------------------------------------------------------------
// generic fp32 -> bf16 stream (8 elems/thread)
__global__ __launch_bounds__(256) void k_cvt(const float* src, unsigned short* dst) {
    size_t i = ((size_t)blockIdx.x * 256 + threadIdx.x) * 8;
    float4 f0 = *(const float4*)(src + i);
    float4 f1 = *(const float4*)(src + i + 4);
    union { bf16x8 v; unsigned u[4]; } r;
    r.u[0] = rne2(f0.x, f0.y); r.u[1] = rne2(f0.z, f0.w);
    r.u[2] = rne2(f1.x, f1.y); r.u[3] = rne2(f1.z, f1.w);
    *(bf16x8*)(dst + i) = r.v;
}

// ---------------------------------------------------------------------------
// WgT[o][k] bf16, o=0..127 (c_out*64+m), k=0..16383 (c_in*8192+n)
// o<64 : [ Ar[m] | -Ai[m] ] ;  o>=64 : [ Ai[m] | Ar[m] ]
__global__ __launch_bounds__(256) void k_prep_wg(const float* A, unsigned short* WgT) {
    int o = blockIdx.x;
    int kb = blockIdx.y * 2048 + threadIdx.x * 8;
    int m = o & 63;
    const float* Ar = A + (size_t)m * N_;
    const float* Ai = A + (size_t)M_ * N_ + (size_t)m * N_;
    bool oimag = o >= 64;
    bool khigh = kb >= N_;
    int koff = khigh ? kb - N_ : kb;
    const float* src = oimag ? (khigh ? Ar : Ai) : (khigh ? Ai : Ar);
    float sgn = (!oimag && khigh) ? -1.f : 1.f;
    float4 f0 = *(const float4*)(src + koff);
    float4 f1 = *(const float4*)(src + koff + 4);
    union { bf16x8 v; unsigned u[4]; } r;
    r.u[0] = rne2(sgn * f0.x, sgn * f0.y); r.u[1] = rne2(sgn * f0.z, sgn * f0.w);
    r.u[2] = rne2(sgn * f1.x, sgn * f1.y); r.u[3] = rne2(sgn * f1.z, sgn * f1.w);
    *(bf16x8*)(WgT + (size_t)o * 16384 + kb) = r.v;
}

// ---------------------------------------------------------------------------
// ATb[n][k] bf16, k = c*64+m : ATb[n][c*64+m] = A[c][m][n]
__global__ __launch_bounds__(256) void k_transpA(const float* A, unsigned short* ATb) {
    __shared__ float tile[128][65];
    int n0 = blockIdx.x * 64;
    int t = threadIdx.x;
    int nl = t % 64, r0 = t / 64;
    for (int it = 0; it < 32; ++it) {
        int row = r0 + it * 4;                       // row = c*64+m
        tile[row][nl] = A[(size_t)row * N_ + n0 + nl];
    }
    __syncthreads();
    int o = t % 128, nn0 = t / 128;
    for (int it = 0; it < 32; ++it) {
        int nn = nn0 + it * 2;
        ATb[(size_t)(n0 + nn) * 128 + o] = f2b(tile[o][nn]);
    }
}

// ---------------------------------------------------------------------------
// S = I/(rho+1e-12) + A A^H  (complex 64x64, Hermitian). fp32.
__global__ __launch_bounds__(256) void k_Sbuild(const float* A, const float* lr,
                                                float* S, float* AAHT) {
    __shared__ float redS[8];
    int bid = blockIdx.x;
    int i = 0, rem = bid;
    while (rem >= 64 - i) { rem -= 64 - i; ++i; }
    int j = i + rem;                       // i <= j
    int t = threadIdx.x;
    const float* Ar = A;
    const float* Ai = A + (size_t)M_ * N_;
    const float* ari = Ar + (size_t)i * N_;
    const float* aii = Ai + (size_t)i * N_;
    const float* arj = Ar + (size_t)j * N_;
    const float* aij = Ai + (size_t)j * N_;
    float aR = 0.f, aI = 0.f;
#pragma unroll
    for (int it = 0; it < 8; ++it) {
        int n = it * 1024 + t * 4;
        float4 xr = *(const float4*)(ari + n);
        float4 xi = *(const float4*)(aii + n);
        float4 br = *(const float4*)(arj + n);
        float4 bi = *(const float4*)(aij + n);
        aR += xr.x * br.x + xi.x * bi.x + xr.y * br.y + xi.y * bi.y
            + xr.z * br.z + xi.z * bi.z + xr.w * br.w + xi.w * bi.w;
        aI += xi.x * br.x - xr.x * bi.x + xi.y * br.y - xr.y * bi.y
            + xi.z * br.z - xr.z * bi.z + xi.w * br.w - xr.w * bi.w;
    }
    for (int off = 32; off > 0; off >>= 1) {
        aR += __shfl_down(aR, off, 64);
        aI += __shfl_down(aI, off, 64);
    }
    int lane = t & 63, w = t >> 6;
    if (lane == 0) { redS[w * 2] = aR; redS[w * 2 + 1] = aI; }
    __syncthreads();
    if (t == 0) {
        float R = redS[0] + redS[2] + redS[4] + redS[6];
        float I = redS[1] + redS[3] + redS[5] + redS[7];
        float inv_rho = 1.0f / (expf(lr[0]) + 1e-12f);
        float diag = (i == j) ? inv_rho : 0.f;
        S[((size_t)i * 64 + j) * 2 + 0] = R + diag;
        S[((size_t)i * 64 + j) * 2 + 1] = I;
        AAHT[((size_t)j * 64 + i) * 2 + 0] = R;
        AAHT[((size_t)j * 64 + i) * 2 + 1] = I;
        if (i != j) {
            S[((size_t)j * 64 + i) * 2 + 0] = R;
            S[((size_t)j * 64 + i) * 2 + 1] = -I;
            AAHT[((size_t)i * 64 + j) * 2 + 0] = R;
            AAHT[((size_t)i * 64 + j) * 2 + 1] = -I;
        }
    }
}

// ---------------------------------------------------------------------------
// Register-resident complex Gauss-Jordan (64x64, well-conditioned, no pivoting).
// 8 waves; lane=row; wave g owns columns 8j+g -> m[16] = 32 VGPRs.
// __launch_bounds__(512,2): 256-VGPR cap, NO spill (r5 lesson).
__global__ __launch_bounds__(512, 2) void k_invert(const float* S, float* Wt) {
    __shared__ float2 fvs[2][64];
    int t = threadIdx.x;
    int lane = t & 63;          // row
    int g = t >> 6;             // wave: owns columns 8j+g
    float2 m[16];
#pragma unroll
    for (int j = 0; j < 16; ++j) {
        int c = 8 * j + g;
        if (c < 64) {
            m[j] = ((const float2*)S)[(size_t)lane * 64 + c];
        } else {
            m[j] = (lane == c - 64) ? make_float2(1.f, 0.f) : make_float2(0.f, 0.f);
        }
    }
#pragma unroll
    for (int k = 0; k < 64; ++k) {
        const int par = k & 1;
        if (g == (k & 7)) fvs[par][lane] = m[k >> 3];   // publish column k (pre-update)
        __syncthreads();
        float2 f = fvs[par][lane];          // M[lane][k]
        float2 p = fvs[par][k];             // M[k][k]
        float d = p.x * p.x + p.y * p.y;
        float id = 1.0f / d;
        float pix = p.x * id, piy = -p.y * id;          // 1/p
        bool isk = (lane == k);
        float a   = isk ? 0.f : 1.f;
        float fpx = isk ? -pix : (f.x * pix - f.y * piy);
        float fpy = isk ? -piy : (f.x * piy + f.y * pix);
#pragma unroll
        for (int j = 0; j < 16; ++j) {
            if (8 * j + g > k) {
                float sx = rl(m[j].x, k);
                float sy = rl(m[j].y, k);
                m[j].x = a * m[j].x - (fpx * sx - fpy * sy);
                m[j].y = a * m[j].y - (fpx * sy + fpy * sx);
            }
        }
    }
#pragma unroll
    for (int j = 8; j < 16; ++j) {
        int c = 8 * j + g;                  // >= 64
        ((float2*)Wt)[(size_t)(c - 64) * 64 + lane] = m[j];   // Wt[k][m=lane]
    }
}

// ---------------------------------------------------------------------------
// k_G: Gpart[split][b][o] = sum_{k in chunk} rnb[b][k] * WgT[o][k]  (bf16 MFMA)
// b-tile 16 -> grid (16,64) = 1024 blocks = 16 waves/CU; 3 loads + 2 MFMA / K-step.
__global__ __launch_bounds__(256) void k_G(const unsigned short* rnb, const unsigned short* WgT,
                                           float* Gpart) {
    int t = threadIdx.x;
    int lane = t & 63;
    int w = t >> 6;
    int l15 = lane & 15;
    int q8 = (lane >> 4) * 8;
    int split = blockIdx.x;
    int b0 = blockIdx.y * 16;
    int k0 = split * 1024;
    f32x4 a00 = {}, a01 = {};
    const unsigned short* x0 = rnb + (size_t)(b0 + l15) * 16384 + k0 + q8;
    const unsigned short* w0 = WgT + (size_t)(w * 32 + l15) * 16384 + k0 + q8;
    const unsigned short* w1 = w0 + (size_t)16 * 16384;
#pragma unroll 8
    for (int ks = 0; ks < 32; ++ks) {
        int kk = ks * 32;
        bf16x8 af0 = *(const bf16x8*)(x0 + kk);
        bf16x8 bf0 = *(const bf16x8*)(w0 + kk);
        bf16x8 bf1 = *(const bf16x8*)(w1 + kk);
        a00 = __builtin_amdgcn_mfma_f32_16x16x32_bf16(af0, bf0, a00, 0, 0, 0);
        a01 = __builtin_amdgcn_mfma_f32_16x16x32_bf16(af0, bf1, a01, 0, 0, 0);
    }
    int row = (lane >> 4) * 4;
    size_t base = (size_t)split * (B_ * 128);
    float* g = Gpart + base + (size_t)(b0 + row) * 128 + w * 32 + l15;
#pragma unroll
    for (int r = 0; r < 4; ++r) {
        g[(size_t)r * 128] = a00[r];
        g[(size_t)r * 128 + 16] = a01[r];
    }
}

// ---------------------------------------------------------------------------
// per-step small: Ab = sum(Gpart) + rho*AAH*(z-u);  qb = bf16(rho*(z-u) - S^-1*Ab)
__global__ __launch_bounds__(256) void k_small12(const float* Gpart, const float* AAHT,
                                                 const float* Wt, const float* zin,
                                                 const float* uin, const float* lr,
                                                 unsigned short* qb) {
    __shared__ float2 AbS[4][64];
    int t = threadIdx.x;
    int m = t & 63;
    int w = __builtin_amdgcn_readfirstlane(t >> 6);
    int b = blockIdx.x * 4 + w;
    float rho = expf(lr[0]);
    float abR = 0.f, abI = 0.f;
    for (int k = 0; k < 64; ++k) {
        float wr = zin[(b * 2 + 0) * 64 + k] - uin[(b * 2 + 0) * 64 + k];
        float wi = zin[(b * 2 + 1) * 64 + k] - uin[(b * 2 + 1) * 64 + k];
        float2 h = *(const float2*)(AAHT + ((size_t)k * 64 + m) * 2);  // AAH[m][k]
        abR += wr * h.x - wi * h.y;
        abI += wi * h.x + wr * h.y;
    }
    float gR = 0.f, gI = 0.f;
#pragma unroll
    for (int s = 0; s < NSG; ++s) {
        gR += Gpart[(size_t)s * 131072 + (size_t)b * 128 + m];
        gI += Gpart[(size_t)s * 131072 + (size_t)b * 128 + 64 + m];
    }
    abR = gR + rho * abR;
    abI = gI + rho * abI;
    AbS[w][m] = make_float2(abR, abI);
    __syncthreads();
    float tR = 0.f, tI = 0.f;
    for (int k = 0; k < 64; ++k) {
        float2 Wv = *(const float2*)(Wt + ((size_t)k * 64 + m) * 2);   // W[m][k]
        float2 ab = AbS[w][k];
        tR += ab.x * Wv.x - ab.y * Wv.y;
        tI += ab.y * Wv.x + ab.x * Wv.y;
    }
    float wr_m = zin[(b * 2 + 0) * 64 + m] - uin[(b * 2 + 0) * 64 + m];
    float wi_m = zin[(b * 2 + 1) * 64 + m] - uin[(b * 2 + 1) * 64 + m];
    qb[(size_t)b * 128 + m] = f2b(rho * wr_m - tR);
    qb[(size_t)b * 128 + 64 + m] = f2b(rho * wi_m - tI);
}

// ---------------------------------------------------------------------------
// k_H23: fused x-update + Ax partials.
// Phase 1 (H2): x[b][n] = relu(rn_r + q·ATb) per wave's 256-col slab; stash x as
//   bf16 in WAVE-PRIVATE LDS (C-layout -> A-layout transpose); fp32 out only if last.
// Phase 2 (H3): Ax_partial[b][o] += x · Abf^T over the slab (K=256), acc 8 o-tiles.
// Phase 3: partials -> LDS (aliases x-stage, same wave), cross-wave reduce,
//   write Axpart[slab][b][128].
// LDS per wave: 8448 B (16 rows x 264 shorts == 16 x 132 floats); 33.8 KB/block.
__global__ __launch_bounds__(256, 3) void k_H23(const unsigned short* qb, const unsigned short* ATb,
                                                const float* rn, const unsigned short* Abf,
                                                float* out, float* Axpart, int last) {
    __shared__ __align__(16) char lds_buf[4 * 8448];
    int t = threadIdx.x;
    int lane = t & 63;
    int w = t >> 6;
    int l15 = lane & 15;
    int q8 = (lane >> 4) * 8;
    int row = (lane >> 4) * 4;
    int slab = blockIdx.x;
    int b0 = blockIdx.y * 16;
    int n0 = slab * 1024 + w * 256;
    short* xs = (short*)(lds_buf + w * 8448);      // [16][264] bf16 (row stride 528B: bank-safe)
    float* rs = (float*)(lds_buf + w * 8448);      // [16][132] fp32 alias (same wave only)

    // ---- phase 1
    bf16x8 a[4];
    const unsigned short* qrow = qb + (size_t)(b0 + l15) * 128 + q8;
#pragma unroll
    for (int ks = 0; ks < 4; ++ks) a[ks] = *(const bf16x8*)(qrow + ks * 32);
#pragma unroll 2
    for (int nt = 0; nt < 16; ++nt) {
        f32x4 acc = {};
        const unsigned short* bbase = ATb + (size_t)(n0 + nt * 16 + l15) * 128 + q8;
#pragma unroll
        for (int ks = 0; ks < 4; ++ks) {
            bf16x8 bf = *(const bf16x8*)(bbase + ks * 32);
            acc = __builtin_amdgcn_mfma_f32_16x16x32_bf16(a[ks], bf, acc, 0, 0, 0);
        }
        int ncol = n0 + nt * 16 + l15;
        int nloc = nt * 16 + l15;
#pragma unroll
        for (int r = 0; r < 4; ++r) {
            size_t ridx = (size_t)(b0 + row + r) * 16384 + ncol;   // real row of rn/out
            float v = fmaxf(acc[r] + rn[ridx], 0.f);
            if (last) out[ridx] = v;
            xs[(row + r) * 264 + nloc] = (short)f2b(v);
        }
    }
    // ---- phase 2 (wave-private x-stage: no barrier needed; lgkmcnt orders RAW)
    f32x4 acc8[8] = {};
#pragma unroll
    for (int ks = 0; ks < 8; ++ks) {
        bf16x8 xf = *(const bf16x8*)(xs + l15 * 264 + ks * 32 + q8);
#pragma unroll
        for (int ot = 0; ot < 8; ++ot) {
            const unsigned short* bp = Abf + (size_t)(ot * 16 + l15) * 8192 + n0 + ks * 32 + q8;
            acc8[ot] = __builtin_amdgcn_mfma_f32_16x16x32_bf16(xf, *(const bf16x8*)bp, acc8[ot], 0, 0, 0);
        }
    }
    // ---- phase 3
    __syncthreads();   // all phase-2 LDS reads done before alias overwrite
#pragma unroll
    for (int ot = 0; ot < 8; ++ot)
#pragma unroll
        for (int r = 0; r < 4; ++r)
            rs[(row + r) * 132 + ot * 16 + l15] = acc8[ot][r];
    __syncthreads();
#pragma unroll
    for (int e = t; e < 2048; e += 256) {
        int b = e >> 7, o = e & 127;
        float sAx = 0.f;
#pragma unroll
        for (int ww = 0; ww < 4; ++ww)
            sAx += ((const float*)(lds_buf + ww * 8448))[b * 132 + o];
        Axpart[(size_t)slab * 131072 + (size_t)(b0 + b) * 128 + o] = sAx;
    }
}

// ---------------------------------------------------------------------------
// per-step epilogue
__global__ __launch_bounds__(128) void k_small3(const float* Axpart, const float* uin,
                                                const float* y, const float* le,
                                                float* z, float* u, float* uout, int last) {
    __shared__ float red[2];
    int b = blockIdx.x, t = threadIdx.x;
    size_t idx = (size_t)b * 128 + t;
    float ax = 0.f;
#pragma unroll
    for (int s = 0; s < NS3; ++s) ax += Axpart[(size_t)s * 131072 + idx];
    float uo = uin[idx], yv = y[idx];
    float v = ax + uo - yv;
    float sq = v * v;
    for (int off = 32; off > 0; off >>= 1) sq += __shfl_down(sq, off, 64);
    if ((t & 63) == 0) red[t >> 6] = sq;
    __syncthreads();
    float tot = red[0] + red[1];
    float eps = expf(le[0]);
    float scale = fminf(1.f, eps / (sqrtf(tot) + 1e-12f));
    float zv = yv + v * scale;
    float un = uo + ax - zv;
    z[idx] = zv;
    u[idx] = un;
    if (last) uout[idx] = un;
}

// ---------------------------------------------------------------------------
extern "C" void kernel_launch(void* const* d_in, const int* in_sizes, int n_in,
                              void* d_out, int out_size, void* d_ws, size_t ws_size,
                              hipStream_t stream) {
    const float* rn  = (const float*)d_in[0];   // (B,2,N)
    const float* y   = (const float*)d_in[1];   // (B,2,M)
    const float* uin = (const float*)d_in[2];   // (B,2,M)
    const float* A   = (const float*)d_in[3];   // (2,M,N)
    const float* lr  = (const float*)d_in[4];   // log_rho
    const float* le  = (const float*)d_in[5];   // log_epsilon

    float* out = (float*)d_out;
    float* ws  = (float*)d_ws;

    float* Gpart  = ws;                             // 16*131072 = 2,097,152 f
    float* Axpart = Gpart + (size_t)NSG * 131072;   //  8*131072 = 1,048,576 f
    float* S      = Axpart + (size_t)NS3 * 131072;  // 8192
    float* AAHT   = S + 8192;                       // 8192
    float* Wt     = AAHT + 8192;                    // 8192
    float* z      = Wt + 8192;                      // 131072
    float* u      = z + 131072;                     // 131072
    unsigned short* qb  = (unsigned short*)(u + 131072);  // 131,072 us
    unsigned short* rnb = qb + 131072;              // B*2*N  = 16,777,216 us
    unsigned short* WgT = rnb + (size_t)B_ * 16384; // 128*16384 = 2,097,152 us
    unsigned short* Abf = WgT + 2097152;            // 2*64*8192 = 1,048,576 us
    unsigned short* ATb = Abf + 1048576;            // 8192*128  = 1,048,576 us
    float* uout = out + (size_t)B_ * 2 * N_;

    k_zero_imag<<<dim3(8, B_), 256, 0, stream>>>(out);
    k_cvt<<<512, 256, 0, stream>>>(A, Abf);
    k_cvt<<<8192, 256, 0, stream>>>(rn, rnb);
    k_prep_wg<<<dim3(128, 8), 256, 0, stream>>>(A, WgT);
    k_transpA<<<128, 256, 0, stream>>>(A, ATb);
    k_Sbuild<<<2080, 256, 0, stream>>>(A, lr, S, AAHT);
    k_invert<<<1, 512, 0, stream>>>(S, Wt);
    k_G<<<dim3(NSG, 64), 256, 0, stream>>>(rnb, WgT, Gpart);

    for (int step = 0; step < 3; ++step) {
        const float* zp = (step == 0) ? y   : z;
        const float* up = (step == 0) ? uin : u;
        int last = (step == 2) ? 1 : 0;
        k_small12<<<256, 256, 0, stream>>>(Gpart, AAHT, Wt, zp, up, lr, qb);
        k_H23<<<dim3(NS3, 64), 256, 0, stream>>>(qb, ATb, rn, Abf, out, Axpart, last);
        k_small3<<<B_, 128, 0, stream>>>(Axpart, up, y, le, z, u, uout, last);
    }
}

// Round 8
// 421.184 us; speedup vs baseline: 1.1861x; 1.1861x over previous
//
#include <hip/hip_runtime.h>

#define B_ 1024
#define M_ 64
#define N_ 8192
#define NSG 16   // k-splits for k_G  (chunk 1024 of K=16384)
#define NS3 8    // n-slabs for k_H23 (1024 cols each)

typedef __attribute__((ext_vector_type(8))) short bf16x8;
typedef __attribute__((ext_vector_type(4))) float f32x4;

__device__ inline unsigned short f2b(float f) {
    union { float f; unsigned u; } v; v.f = f;
    unsigned r = v.u + 0x7FFFu + ((v.u >> 16) & 1u);
    return (unsigned short)(r >> 16);
}
__device__ inline unsigned rne2(float lo, float hi) {
    union { float f; unsigned u; } a, b; a.f = lo; b.f = hi;
    unsigned x = (a.u + 0x7FFFu + ((a.u >> 16) & 1u)) >> 16;
    unsigned y = (b.u + 0x7FFFu + ((b.u >> 16) & 1u)) >> 16;
    return x | (y << 16);
}
// readlane with UNIFORM (possibly dynamic) lane index -> v_readlane_b32 (SALU path)
__device__ inline float rl(float v, int l) {
    return __builtin_bit_cast(float, __builtin_amdgcn_readlane(__builtin_bit_cast(int, v), l));
}

// ---------------------------------------------------------------------------
// zero the imaginary rows of out-x: out[(2b+1)*N + n] = 0
__global__ __launch_bounds__(256) void k_zero_imag(float* out) {
    int b = blockIdx.y;
    int n = (blockIdx.x * 256 + threadIdx.x) * 4;
    float4 z = make_float4(0.f, 0.f, 0.f, 0.f);
    *(float4*)(out + (size_t)(2 * b + 1) * N_ + n) = z;
}

// ---------------------------------------------------------------------------
// generic fp32 -> bf16 stream (8 elems/thread)
__global__ __launch_bounds__(256) void k_cvt(const float* src, unsigned short* dst) {
    size_t i = ((size_t)blockIdx.x * 256 + threadIdx.x) * 8;
    float4 f0 = *(const float4*)(src + i);
    float4 f1 = *(const float4*)(src + i + 4);
    union { bf16x8 v; unsigned u[4]; } r;
    r.u[0] = rne2(f0.x, f0.y); r.u[1] = rne2(f0.z, f0.w);
    r.u[2] = rne2(f1.x, f1.y); r.u[3] = rne2(f1.z, f1.w);
    *(bf16x8*)(dst + i) = r.v;
}

// ---------------------------------------------------------------------------
// WgT[o][k] bf16, o=0..127 (c_out*64+m), k=0..16383 (c_in*8192+n)
// o<64 : [ Ar[m] | -Ai[m] ] ;  o>=64 : [ Ai[m] | Ar[m] ]
__global__ __launch_bounds__(256) void k_prep_wg(const float* A, unsigned short* WgT) {
    int o = blockIdx.x;
    int kb = blockIdx.y * 2048 + threadIdx.x * 8;
    int m = o & 63;
    const float* Ar = A + (size_t)m * N_;
    const float* Ai = A + (size_t)M_ * N_ + (size_t)m * N_;
    bool oimag = o >= 64;
    bool khigh = kb >= N_;
    int koff = khigh ? kb - N_ : kb;
    const float* src = oimag ? (khigh ? Ar : Ai) : (khigh ? Ai : Ar);
    float sgn = (!oimag && khigh) ? -1.f : 1.f;
    float4 f0 = *(const float4*)(src + koff);
    float4 f1 = *(const float4*)(src + koff + 4);
    union { bf16x8 v; unsigned u[4]; } r;
    r.u[0] = rne2(sgn * f0.x, sgn * f0.y); r.u[1] = rne2(sgn * f0.z, sgn * f0.w);
    r.u[2] = rne2(sgn * f1.x, sgn * f1.y); r.u[3] = rne2(sgn * f1.z, sgn * f1.w);
    *(bf16x8*)(WgT + (size_t)o * 16384 + kb) = r.v;
}

// ---------------------------------------------------------------------------
// ATb[n][k] bf16, k = c*64+m : ATb[n][c*64+m] = A[c][m][n]
__global__ __launch_bounds__(256) void k_transpA(const float* A, unsigned short* ATb) {
    __shared__ float tile[128][65];
    int n0 = blockIdx.x * 64;
    int t = threadIdx.x;
    int nl = t % 64, r0 = t / 64;
    for (int it = 0; it < 32; ++it) {
        int row = r0 + it * 4;                       // row = c*64+m
        tile[row][nl] = A[(size_t)row * N_ + n0 + nl];
    }
    __syncthreads();
    int o = t % 128, nn0 = t / 128;
    for (int it = 0; it < 32; ++it) {
        int nn = nn0 + it * 2;
        ATb[(size_t)(n0 + nn) * 128 + o] = f2b(tile[o][nn]);
    }
}

// ---------------------------------------------------------------------------
// S = I/(rho+1e-12) + A A^H  (complex 64x64, Hermitian). fp32.
__global__ __launch_bounds__(256) void k_Sbuild(const float* A, const float* lr,
                                                float* S, float* AAHT) {
    __shared__ float redS[8];
    int bid = blockIdx.x;
    int i = 0, rem = bid;
    while (rem >= 64 - i) { rem -= 64 - i; ++i; }
    int j = i + rem;                       // i <= j
    int t = threadIdx.x;
    const float* Ar = A;
    const float* Ai = A + (size_t)M_ * N_;
    const float* ari = Ar + (size_t)i * N_;
    const float* aii = Ai + (size_t)i * N_;
    const float* arj = Ar + (size_t)j * N_;
    const float* aij = Ai + (size_t)j * N_;
    float aR = 0.f, aI = 0.f;
#pragma unroll
    for (int it = 0; it < 8; ++it) {
        int n = it * 1024 + t * 4;
        float4 xr = *(const float4*)(ari + n);
        float4 xi = *(const float4*)(aii + n);
        float4 br = *(const float4*)(arj + n);
        float4 bi = *(const float4*)(aij + n);
        aR += xr.x * br.x + xi.x * bi.x + xr.y * br.y + xi.y * bi.y
            + xr.z * br.z + xi.z * bi.z + xr.w * br.w + xi.w * bi.w;
        aI += xi.x * br.x - xr.x * bi.x + xi.y * br.y - xr.y * bi.y
            + xi.z * br.z - xr.z * bi.z + xi.w * br.w - xr.w * bi.w;
    }
    for (int off = 32; off > 0; off >>= 1) {
        aR += __shfl_down(aR, off, 64);
        aI += __shfl_down(aI, off, 64);
    }
    int lane = t & 63, w = t >> 6;
    if (lane == 0) { redS[w * 2] = aR; redS[w * 2 + 1] = aI; }
    __syncthreads();
    if (t == 0) {
        float R = redS[0] + redS[2] + redS[4] + redS[6];
        float I = redS[1] + redS[3] + redS[5] + redS[7];
        float inv_rho = 1.0f / (expf(lr[0]) + 1e-12f);
        float diag = (i == j) ? inv_rho : 0.f;
        S[((size_t)i * 64 + j) * 2 + 0] = R + diag;
        S[((size_t)i * 64 + j) * 2 + 1] = I;
        AAHT[((size_t)j * 64 + i) * 2 + 0] = R;
        AAHT[((size_t)j * 64 + i) * 2 + 1] = I;
        if (i != j) {
            S[((size_t)j * 64 + i) * 2 + 0] = R;
            S[((size_t)j * 64 + i) * 2 + 1] = -I;
            AAHT[((size_t)i * 64 + j) * 2 + 0] = R;
            AAHT[((size_t)i * 64 + j) * 2 + 1] = -I;
        }
    }
}

// ---------------------------------------------------------------------------
// Complex Gauss-Jordan inverse, 64x64, no pivoting (S diag-dominant).
// ROBUST register residency: 16 waves, wave g owns columns c=16j+g held in
// 16 NAMED scalars (mx0..my7) — no array, no indexing, nothing to spill,
// regardless of unroll decisions (r7 failure: unroll heuristic flip made
// m[k>>3] dynamic -> scratch). Pivot row via v_readlane with DYNAMIC uniform
// lane k (SALU form). Dead columns updated unconditionally (never read again).
// Wt[k][m] = (S^-1)[m][k]
__global__ __launch_bounds__(1024) void k_invert(const float* S, float* Wt) {
    __shared__ float2 fvs[2][64];
    int t = threadIdx.x;
    int lane = t & 63;          // row
    int g = t >> 6;             // wave 0..15: owns columns 16j+g, j=0..7
    float mx0, my0, mx1, my1, mx2, my2, mx3, my3;
    float mx4, my4, mx5, my5, mx6, my6, mx7, my7;
#define GJ_INIT(J) { int c = 16 * (J) + g;                                   \
    if (c < 64) { float2 v = ((const float2*)S)[(size_t)lane * 64 + c];      \
                  mx##J = v.x; my##J = v.y; }                                \
    else { mx##J = (lane == c - 64) ? 1.f : 0.f; my##J = 0.f; } }
    GJ_INIT(0) GJ_INIT(1) GJ_INIT(2) GJ_INIT(3)
    GJ_INIT(4) GJ_INIT(5) GJ_INIT(6) GJ_INIT(7)
#undef GJ_INIT
    for (int k = 0; k < 64; ++k) {
        const int par = k & 1;
        if (g == (k & 15)) {               // publish column k (pre-update value)
            switch (k >> 4) {
                case 0: fvs[par][lane] = make_float2(mx0, my0); break;
                case 1: fvs[par][lane] = make_float2(mx1, my1); break;
                case 2: fvs[par][lane] = make_float2(mx2, my2); break;
                default: fvs[par][lane] = make_float2(mx3, my3); break;
            }
        }
        __syncthreads();
        float2 f = fvs[par][lane];          // M[lane][k]
        float2 p = fvs[par][k];             // M[k][k]
        float d = p.x * p.x + p.y * p.y;
        float id = 1.0f / d;
        float pix = p.x * id, piy = -p.y * id;          // 1/pivot
        bool isk = (lane == k);
        // unified: m' = a*m - fp (x) srow ; pivot row (lane k): a=0, fp=-pinv
        float a   = isk ? 0.f : 1.f;
        float fpx = isk ? -pix : (f.x * pix - f.y * piy);
        float fpy = isk ? -piy : (f.x * piy + f.y * pix);
#define GJ_UP(J) { float sx = rl(mx##J, k), sy = rl(my##J, k);               \
    float nx = a * mx##J - (fpx * sx - fpy * sy);                            \
    float ny = a * my##J - (fpx * sy + fpy * sx);                            \
    mx##J = nx; my##J = ny; }
        GJ_UP(0) GJ_UP(1) GJ_UP(2) GJ_UP(3)
        GJ_UP(4) GJ_UP(5) GJ_UP(6) GJ_UP(7)
#undef GJ_UP
        // no trailing barrier: parity double-buffer (WAR separated by 2 barriers)
    }
#define GJ_OUT(J) { int c = 16 * (J) + g;                                    \
    ((float2*)Wt)[(size_t)(c - 64) * 64 + lane] = make_float2(mx##J, my##J); }
    GJ_OUT(4) GJ_OUT(5) GJ_OUT(6) GJ_OUT(7)
#undef GJ_OUT
}

// ---------------------------------------------------------------------------
// k_G: Gpart[split][b][o] = sum_{k in chunk} rnb[b][k] * WgT[o][k]  (bf16 MFMA)
__global__ __launch_bounds__(256) void k_G(const unsigned short* rnb, const unsigned short* WgT,
                                           float* Gpart) {
    int t = threadIdx.x;
    int lane = t & 63;
    int w = t >> 6;
    int l15 = lane & 15;
    int q8 = (lane >> 4) * 8;
    int split = blockIdx.x;
    int b0 = blockIdx.y * 16;
    int k0 = split * 1024;
    f32x4 a00 = {}, a01 = {};
    const unsigned short* x0 = rnb + (size_t)(b0 + l15) * 16384 + k0 + q8;
    const unsigned short* w0 = WgT + (size_t)(w * 32 + l15) * 16384 + k0 + q8;
    const unsigned short* w1 = w0 + (size_t)16 * 16384;
#pragma unroll 8
    for (int ks = 0; ks < 32; ++ks) {
        int kk = ks * 32;
        bf16x8 af0 = *(const bf16x8*)(x0 + kk);
        bf16x8 bf0 = *(const bf16x8*)(w0 + kk);
        bf16x8 bf1 = *(const bf16x8*)(w1 + kk);
        a00 = __builtin_amdgcn_mfma_f32_16x16x32_bf16(af0, bf0, a00, 0, 0, 0);
        a01 = __builtin_amdgcn_mfma_f32_16x16x32_bf16(af0, bf1, a01, 0, 0, 0);
    }
    int row = (lane >> 4) * 4;
    size_t base = (size_t)split * (B_ * 128);
    float* g = Gpart + base + (size_t)(b0 + row) * 128 + w * 32 + l15;
#pragma unroll
    for (int r = 0; r < 4; ++r) {
        g[(size_t)r * 128] = a00[r];
        g[(size_t)r * 128 + 16] = a01[r];
    }
}

// ---------------------------------------------------------------------------
// per-step small: Ab = sum(Gpart) + rho*AAH*(z-u);  qb = bf16(rho*(z-u) - S^-1*Ab)
__global__ __launch_bounds__(256) void k_small12(const float* Gpart, const float* AAHT,
                                                 const float* Wt, const float* zin,
                                                 const float* uin, const float* lr,
                                                 unsigned short* qb) {
    __shared__ float2 AbS[4][64];
    int t = threadIdx.x;
    int m = t & 63;
    int w = __builtin_amdgcn_readfirstlane(t >> 6);
    int b = blockIdx.x * 4 + w;
    float rho = expf(lr[0]);
    float abR = 0.f, abI = 0.f;
    for (int k = 0; k < 64; ++k) {
        float wr = zin[(b * 2 + 0) * 64 + k] - uin[(b * 2 + 0) * 64 + k];
        float wi = zin[(b * 2 + 1) * 64 + k] - uin[(b * 2 + 1) * 64 + k];
        float2 h = *(const float2*)(AAHT + ((size_t)k * 64 + m) * 2);  // AAH[m][k]
        abR += wr * h.x - wi * h.y;
        abI += wi * h.x + wr * h.y;
    }
    float gR = 0.f, gI = 0.f;
#pragma unroll
    for (int s = 0; s < NSG; ++s) {
        gR += Gpart[(size_t)s * 131072 + (size_t)b * 128 + m];
        gI += Gpart[(size_t)s * 131072 + (size_t)b * 128 + 64 + m];
    }
    abR = gR + rho * abR;
    abI = gI + rho * abI;
    AbS[w][m] = make_float2(abR, abI);
    __syncthreads();
    float tR = 0.f, tI = 0.f;
    for (int k = 0; k < 64; ++k) {
        float2 Wv = *(const float2*)(Wt + ((size_t)k * 64 + m) * 2);   // W[m][k]
        float2 ab = AbS[w][k];
        tR += ab.x * Wv.x - ab.y * Wv.y;
        tI += ab.y * Wv.x + ab.x * Wv.y;
    }
    float wr_m = zin[(b * 2 + 0) * 64 + m] - uin[(b * 2 + 0) * 64 + m];
    float wi_m = zin[(b * 2 + 1) * 64 + m] - uin[(b * 2 + 1) * 64 + m];
    qb[(size_t)b * 128 + m] = f2b(rho * wr_m - tR);
    qb[(size_t)b * 128 + 64 + m] = f2b(rho * wi_m - tI);
}

// ---------------------------------------------------------------------------
// k_H23: fused x-update + Ax partials (see r6 notes).
__global__ __launch_bounds__(256, 3) void k_H23(const unsigned short* qb, const unsigned short* ATb,
                                                const float* rn, const unsigned short* Abf,
                                                float* out, float* Axpart, int last) {
    __shared__ __align__(16) char lds_buf[4 * 8448];
    int t = threadIdx.x;
    int lane = t & 63;
    int w = t >> 6;
    int l15 = lane & 15;
    int q8 = (lane >> 4) * 8;
    int row = (lane >> 4) * 4;
    int slab = blockIdx.x;
    int b0 = blockIdx.y * 16;
    int n0 = slab * 1024 + w * 256;
    short* xs = (short*)(lds_buf + w * 8448);      // [16][264] bf16 (row stride 528B)
    float* rs = (float*)(lds_buf + w * 8448);      // [16][132] fp32 alias (same wave only)

    // ---- phase 1
    bf16x8 a[4];
    const unsigned short* qrow = qb + (size_t)(b0 + l15) * 128 + q8;
#pragma unroll
    for (int ks = 0; ks < 4; ++ks) a[ks] = *(const bf16x8*)(qrow + ks * 32);
#pragma unroll 2
    for (int nt = 0; nt < 16; ++nt) {
        f32x4 acc = {};
        const unsigned short* bbase = ATb + (size_t)(n0 + nt * 16 + l15) * 128 + q8;
#pragma unroll
        for (int ks = 0; ks < 4; ++ks) {
            bf16x8 bf = *(const bf16x8*)(bbase + ks * 32);
            acc = __builtin_amdgcn_mfma_f32_16x16x32_bf16(a[ks], bf, acc, 0, 0, 0);
        }
        int ncol = n0 + nt * 16 + l15;
        int nloc = nt * 16 + l15;
#pragma unroll
        for (int r = 0; r < 4; ++r) {
            size_t ridx = (size_t)(b0 + row + r) * 16384 + ncol;   // real row of rn/out
            float v = fmaxf(acc[r] + rn[ridx], 0.f);
            if (last) out[ridx] = v;
            xs[(row + r) * 264 + nloc] = (short)f2b(v);
        }
    }
    // ---- phase 2 (wave-private x-stage: lgkmcnt orders RAW)
    f32x4 acc8[8] = {};
#pragma unroll
    for (int ks = 0; ks < 8; ++ks) {
        bf16x8 xf = *(const bf16x8*)(xs + l15 * 264 + ks * 32 + q8);
#pragma unroll
        for (int ot = 0; ot < 8; ++ot) {
            const unsigned short* bp = Abf + (size_t)(ot * 16 + l15) * 8192 + n0 + ks * 32 + q8;
            acc8[ot] = __builtin_amdgcn_mfma_f32_16x16x32_bf16(xf, *(const bf16x8*)bp, acc8[ot], 0, 0, 0);
        }
    }
    // ---- phase 3
    __syncthreads();
#pragma unroll
    for (int ot = 0; ot < 8; ++ot)
#pragma unroll
        for (int r = 0; r < 4; ++r)
            rs[(row + r) * 132 + ot * 16 + l15] = acc8[ot][r];
    __syncthreads();
#pragma unroll
    for (int e = t; e < 2048; e += 256) {
        int b = e >> 7, o = e & 127;
        float sAx = 0.f;
#pragma unroll
        for (int ww = 0; ww < 4; ++ww)
            sAx += ((const float*)(lds_buf + ww * 8448))[b * 132 + o];
        Axpart[(size_t)slab * 131072 + (size_t)(b0 + b) * 128 + o] = sAx;
    }
}

// ---------------------------------------------------------------------------
// per-step epilogue
__global__ __launch_bounds__(128) void k_small3(const float* Axpart, const float* uin,
                                                const float* y, const float* le,
                                                float* z, float* u, float* uout, int last) {
    __shared__ float red[2];
    int b = blockIdx.x, t = threadIdx.x;
    size_t idx = (size_t)b * 128 + t;
    float ax = 0.f;
#pragma unroll
    for (int s = 0; s < NS3; ++s) ax += Axpart[(size_t)s * 131072 + idx];
    float uo = uin[idx], yv = y[idx];
    float v = ax + uo - yv;
    float sq = v * v;
    for (int off = 32; off > 0; off >>= 1) sq += __shfl_down(sq, off, 64);
    if ((t & 63) == 0) red[t >> 6] = sq;
    __syncthreads();
    float tot = red[0] + red[1];
    float eps = expf(le[0]);
    float scale = fminf(1.f, eps / (sqrtf(tot) + 1e-12f));
    float zv = yv + v * scale;
    float un = uo + ax - zv;
    z[idx] = zv;
    u[idx] = un;
    if (last) uout[idx] = un;
}

// ---------------------------------------------------------------------------
extern "C" void kernel_launch(void* const* d_in, const int* in_sizes, int n_in,
                              void* d_out, int out_size, void* d_ws, size_t ws_size,
                              hipStream_t stream) {
    const float* rn  = (const float*)d_in[0];   // (B,2,N)
    const float* y   = (const float*)d_in[1];   // (B,2,M)
    const float* uin = (const float*)d_in[2];   // (B,2,M)
    const float* A   = (const float*)d_in[3];   // (2,M,N)
    const float* lr  = (const float*)d_in[4];   // log_rho
    const float* le  = (const float*)d_in[5];   // log_epsilon

    float* out = (float*)d_out;
    float* ws  = (float*)d_ws;

    float* Gpart  = ws;                             // 16*131072 = 2,097,152 f
    float* Axpart = Gpart + (size_t)NSG * 131072;   //  8*131072 = 1,048,576 f
    float* S      = Axpart + (size_t)NS3 * 131072;  // 8192
    float* AAHT   = S + 8192;                       // 8192
    float* Wt     = AAHT + 8192;                    // 8192
    float* z      = Wt + 8192;                      // 131072
    float* u      = z + 131072;                     // 131072
    unsigned short* qb  = (unsigned short*)(u + 131072);  // 131,072 us
    unsigned short* rnb = qb + 131072;              // B*2*N  = 16,777,216 us
    unsigned short* WgT = rnb + (size_t)B_ * 16384; // 128*16384 = 2,097,152 us
    unsigned short* Abf = WgT + 2097152;            // 2*64*8192 = 1,048,576 us
    unsigned short* ATb = Abf + 1048576;            // 8192*128  = 1,048,576 us
    float* uout = out + (size_t)B_ * 2 * N_;

    k_zero_imag<<<dim3(8, B_), 256, 0, stream>>>(out);
    k_cvt<<<512, 256, 0, stream>>>(A, Abf);
    k_cvt<<<8192, 256, 0, stream>>>(rn, rnb);
    k_prep_wg<<<dim3(128, 8), 256, 0, stream>>>(A, WgT);
    k_transpA<<<128, 256, 0, stream>>>(A, ATb);
    k_Sbuild<<<2080, 256, 0, stream>>>(A, lr, S, AAHT);
    k_invert<<<1, 1024, 0, stream>>>(S, Wt);
    k_G<<<dim3(NSG, 64), 256, 0, stream>>>(rnb, WgT, Gpart);

    for (int step = 0; step < 3; ++step) {
        const float* zp = (step == 0) ? y   : z;
        const float* up = (step == 0) ? uin : u;
        int last = (step == 2) ? 1 : 0;
        k_small12<<<256, 256, 0, stream>>>(Gpart, AAHT, Wt, zp, up, lr, qb);
        k_H23<<<dim3(NS3, 64), 256, 0, stream>>>(qb, ATb, rn, Abf, out, Axpart, last);
        k_small3<<<B_, 128, 0, stream>>>(Axpart, up, y, le, z, u, uout, last);
    }
}

// Round 9
// 408.975 us; speedup vs baseline: 1.2215x; 1.0299x over previous
//
#include <hip/hip_runtime.h>

#define B_ 1024
#define M_ 64
#define N_ 8192
#define NSG 16   // k-splits for k_G  (chunk 1024 of K=16384)
#define NS3 8    // n-slabs for k_H23 (1024 cols each)

typedef __attribute__((ext_vector_type(8))) short bf16x8;
typedef __attribute__((ext_vector_type(4))) float f32x4;

__device__ inline unsigned short f2b(float f) {
    union { float f; unsigned u; } v; v.f = f;
    unsigned r = v.u + 0x7FFFu + ((v.u >> 16) & 1u);
    return (unsigned short)(r >> 16);
}
__device__ inline unsigned rne2(float lo, float hi) {
    union { float f; unsigned u; } a, b; a.f = lo; b.f = hi;
    unsigned x = (a.u + 0x7FFFu + ((a.u >> 16) & 1u)) >> 16;
    unsigned y = (b.u + 0x7FFFu + ((b.u >> 16) & 1u)) >> 16;
    return x | (y << 16);
}
__device__ inline float b2f(unsigned short s) {
    union { unsigned u; float f; } v; v.u = ((unsigned)s) << 16; return v.f;
}
// readlane with uniform (dynamic) lane index -> SALU broadcast (r8-proven)
__device__ inline float rl(float v, int l) {
    return __builtin_bit_cast(float, __builtin_amdgcn_readlane(__builtin_bit_cast(int, v), l));
}

// ---------------------------------------------------------------------------
// generic fp32 -> bf16 stream (8 elems/thread)
__global__ __launch_bounds__(256) void k_cvt(const float* src, unsigned short* dst) {
    size_t i = ((size_t)blockIdx.x * 256 + threadIdx.x) * 8;
    float4 f0 = *(const float4*)(src + i);
    float4 f1 = *(const float4*)(src + i + 4);
    union { bf16x8 v; unsigned u[4]; } r;
    r.u[0] = rne2(f0.x, f0.y); r.u[1] = rne2(f0.z, f0.w);
    r.u[2] = rne2(f1.x, f1.y); r.u[3] = rne2(f1.z, f1.w);
    *(bf16x8*)(dst + i) = r.v;
}

// ---------------------------------------------------------------------------
// Fused A-prep: one pass over A produces Abf (bf16 copy), ATb (transpose,
// [n][c*64+m]), WgT ([o][k]: o<64 -> [Ar|-Ai], o>=64 -> [Ai|Ar]).
__global__ __launch_bounds__(256) void k_prep(const float* A, unsigned short* Abf,
                                              unsigned short* WgT, unsigned short* ATb) {
    __shared__ float tile[128][65];
    int n0 = blockIdx.x * 64;
    int t = threadIdx.x;
    int nl = t % 64, r0 = t / 64;
#pragma unroll
    for (int it = 0; it < 32; ++it) {
        int row = r0 + it * 4;                       // row = c*64+m
        tile[row][nl] = A[(size_t)row * N_ + n0 + nl];
    }
    __syncthreads();
    // Abf + WgT (row-major reads of tile)
#pragma unroll
    for (int it = 0; it < 32; ++it) {
        int row = r0 + it * 4;
        float v = tile[row][nl];
        unsigned short bv = f2b(v);
        Abf[(size_t)row * N_ + n0 + nl] = bv;
        if (row < 64) {   // Ar[m]
            WgT[(size_t)row * 16384 + n0 + nl] = bv;                 // o=m,    k-low
            WgT[(size_t)(64 + row) * 16384 + 8192 + n0 + nl] = bv;   // o=64+m, k-high
        } else {          // Ai[m], m=row-64
            int m = row - 64;
            WgT[(size_t)m * 16384 + 8192 + n0 + nl] = f2b(-v);       // o=m,    k-high
            WgT[(size_t)(64 + m) * 16384 + n0 + nl] = bv;            // o=64+m, k-low
        }
    }
    // ATb (transposed reads)
    int o = t % 128, nn0 = t / 128;
#pragma unroll
    for (int it = 0; it < 32; ++it) {
        int nn = nn0 + it * 2;
        ATb[(size_t)(n0 + nn) * 128 + o] = f2b(tile[o][nn]);
    }
}

// ---------------------------------------------------------------------------
// S = I/(rho+1e-12) + A A^H  (complex 64x64, Hermitian). fp32.
__global__ __launch_bounds__(256) void k_Sbuild(const float* A, const float* lr,
                                                float* S, float* AAHT) {
    __shared__ float redS[8];
    int bid = blockIdx.x;
    int i = 0, rem = bid;
    while (rem >= 64 - i) { rem -= 64 - i; ++i; }
    int j = i + rem;                       // i <= j
    int t = threadIdx.x;
    const float* Ar = A;
    const float* Ai = A + (size_t)M_ * N_;
    const float* ari = Ar + (size_t)i * N_;
    const float* aii = Ai + (size_t)i * N_;
    const float* arj = Ar + (size_t)j * N_;
    const float* aij = Ai + (size_t)j * N_;
    float aR = 0.f, aI = 0.f;
#pragma unroll
    for (int it = 0; it < 8; ++it) {
        int n = it * 1024 + t * 4;
        float4 xr = *(const float4*)(ari + n);
        float4 xi = *(const float4*)(aii + n);
        float4 br = *(const float4*)(arj + n);
        float4 bi = *(const float4*)(aij + n);
        aR += xr.x * br.x + xi.x * bi.x + xr.y * br.y + xi.y * bi.y
            + xr.z * br.z + xi.z * bi.z + xr.w * br.w + xi.w * bi.w;
        aI += xi.x * br.x - xr.x * bi.x + xi.y * br.y - xr.y * bi.y
            + xi.z * br.z - xr.z * bi.z + xi.w * br.w - xr.w * bi.w;
    }
    for (int off = 32; off > 0; off >>= 1) {
        aR += __shfl_down(aR, off, 64);
        aI += __shfl_down(aI, off, 64);
    }
    int lane = t & 63, w = t >> 6;
    if (lane == 0) { redS[w * 2] = aR; redS[w * 2 + 1] = aI; }
    __syncthreads();
    if (t == 0) {
        float R = redS[0] + redS[2] + redS[4] + redS[6];
        float I = redS[1] + redS[3] + redS[5] + redS[7];
        float inv_rho = 1.0f / (expf(lr[0]) + 1e-12f);
        float diag = (i == j) ? inv_rho : 0.f;
        S[((size_t)i * 64 + j) * 2 + 0] = R + diag;
        S[((size_t)i * 64 + j) * 2 + 1] = I;
        AAHT[((size_t)j * 64 + i) * 2 + 0] = R;
        AAHT[((size_t)j * 64 + i) * 2 + 1] = I;
        if (i != j) {
            S[((size_t)j * 64 + i) * 2 + 0] = R;
            S[((size_t)j * 64 + i) * 2 + 1] = -I;
            AAHT[((size_t)i * 64 + j) * 2 + 0] = R;
            AAHT[((size_t)i * 64 + j) * 2 + 1] = -I;
        }
    }
}

// ---------------------------------------------------------------------------
// k_Ginv: heterogeneous fused kernel.
//   blocks 0..1023 : Gpart[split][b][o] = sum_k rnb[b][k] * WgT[o][k] (MFMA)
//   block  1024    : complex Gauss-Jordan inverse of S -> Wt (4 waves, 32
//                    named-scalar columns/wave interleaved c=4j+g, dead-col
//                    skip; runs in the GEMM's latency shadow -> ~free)
// launch_bounds(256,2): VGPR cap 256 so the GJ's ~80 live regs never spill
// (r5/r7 lessons), while k_G path (~60 regs) keeps >=4 blocks/CU.
__global__ __launch_bounds__(256, 2) void k_Ginv(const unsigned short* rnb,
                                                 const unsigned short* WgT,
                                                 float* Gpart,
                                                 const float* S, float* Wt) {
    int t = threadIdx.x;
    int lane = t & 63;
    if (blockIdx.x == 1024) {
        // ---------------- inversion path ----------------
        __shared__ float2 fvs[2][64];
        int g = t >> 6;             // wave 0..3: owns columns 4j+g, j=0..31
        float mx0,my0,mx1,my1,mx2,my2,mx3,my3,mx4,my4,mx5,my5,mx6,my6,mx7,my7;
        float mx8,my8,mx9,my9,mx10,my10,mx11,my11,mx12,my12,mx13,my13,mx14,my14,mx15,my15;
        float mx16,my16,mx17,my17,mx18,my18,mx19,my19,mx20,my20,mx21,my21,mx22,my22,mx23,my23;
        float mx24,my24,mx25,my25,mx26,my26,mx27,my27,mx28,my28,mx29,my29,mx30,my30,mx31,my31;
#define GJ_INIT(J) { int c = 4 * (J) + g;                                    \
    if (c < 64) { float2 v = ((const float2*)S)[(size_t)lane * 64 + c];      \
                  mx##J = v.x; my##J = v.y; }                                \
    else { mx##J = (lane == c - 64) ? 1.f : 0.f; my##J = 0.f; } }
        GJ_INIT(0) GJ_INIT(1) GJ_INIT(2) GJ_INIT(3) GJ_INIT(4) GJ_INIT(5) GJ_INIT(6) GJ_INIT(7)
        GJ_INIT(8) GJ_INIT(9) GJ_INIT(10) GJ_INIT(11) GJ_INIT(12) GJ_INIT(13) GJ_INIT(14) GJ_INIT(15)
        GJ_INIT(16) GJ_INIT(17) GJ_INIT(18) GJ_INIT(19) GJ_INIT(20) GJ_INIT(21) GJ_INIT(22) GJ_INIT(23)
        GJ_INIT(24) GJ_INIT(25) GJ_INIT(26) GJ_INIT(27) GJ_INIT(28) GJ_INIT(29) GJ_INIT(30) GJ_INIT(31)
#undef GJ_INIT
        for (int k = 0; k < 64; ++k) {
            const int par = k & 1;
            if (g == (k & 3)) {              // publish column k (pre-update)
                switch (k >> 2) {
                    case 0:  fvs[par][lane] = make_float2(mx0,  my0);  break;
                    case 1:  fvs[par][lane] = make_float2(mx1,  my1);  break;
                    case 2:  fvs[par][lane] = make_float2(mx2,  my2);  break;
                    case 3:  fvs[par][lane] = make_float2(mx3,  my3);  break;
                    case 4:  fvs[par][lane] = make_float2(mx4,  my4);  break;
                    case 5:  fvs[par][lane] = make_float2(mx5,  my5);  break;
                    case 6:  fvs[par][lane] = make_float2(mx6,  my6);  break;
                    case 7:  fvs[par][lane] = make_float2(mx7,  my7);  break;
                    case 8:  fvs[par][lane] = make_float2(mx8,  my8);  break;
                    case 9:  fvs[par][lane] = make_float2(mx9,  my9);  break;
                    case 10: fvs[par][lane] = make_float2(mx10, my10); break;
                    case 11: fvs[par][lane] = make_float2(mx11, my11); break;
                    case 12: fvs[par][lane] = make_float2(mx12, my12); break;
                    case 13: fvs[par][lane] = make_float2(mx13, my13); break;
                    case 14: fvs[par][lane] = make_float2(mx14, my14); break;
                    default: fvs[par][lane] = make_float2(mx15, my15); break;
                }
            }
            __syncthreads();
            float2 f = fvs[par][lane];          // M[lane][k]
            float2 p = fvs[par][k];             // M[k][k]
            float d = p.x * p.x + p.y * p.y;
            float id = 1.0f / d;
            float pix = p.x * id, piy = -p.y * id;          // 1/pivot
            bool isk = (lane == k);
            float a   = isk ? 0.f : 1.f;
            float fpx = isk ? -pix : (f.x * pix - f.y * piy);
            float fpy = isk ? -piy : (f.x * piy + f.y * pix);
#define GJ_UP(J) if (4 * (J) + g > k) {                                      \
    float sx = rl(mx##J, k), sy = rl(my##J, k);                              \
    float nx = a * mx##J - (fpx * sx - fpy * sy);                            \
    float ny = a * my##J - (fpx * sy + fpy * sx);                            \
    mx##J = nx; my##J = ny; }
            GJ_UP(0) GJ_UP(1) GJ_UP(2) GJ_UP(3) GJ_UP(4) GJ_UP(5) GJ_UP(6) GJ_UP(7)
            GJ_UP(8) GJ_UP(9) GJ_UP(10) GJ_UP(11) GJ_UP(12) GJ_UP(13) GJ_UP(14) GJ_UP(15)
            GJ_UP(16) GJ_UP(17) GJ_UP(18) GJ_UP(19) GJ_UP(20) GJ_UP(21) GJ_UP(22) GJ_UP(23)
            GJ_UP(24) GJ_UP(25) GJ_UP(26) GJ_UP(27) GJ_UP(28) GJ_UP(29) GJ_UP(30) GJ_UP(31)
#undef GJ_UP
        }
#define GJ_OUT(J) { int c = 4 * (J) + g;                                     \
    ((float2*)Wt)[(size_t)(c - 64) * 64 + lane] = make_float2(mx##J, my##J); }
        GJ_OUT(16) GJ_OUT(17) GJ_OUT(18) GJ_OUT(19) GJ_OUT(20) GJ_OUT(21) GJ_OUT(22) GJ_OUT(23)
        GJ_OUT(24) GJ_OUT(25) GJ_OUT(26) GJ_OUT(27) GJ_OUT(28) GJ_OUT(29) GJ_OUT(30) GJ_OUT(31)
#undef GJ_OUT
        return;
    }
    // ---------------- GEMM path (k_G) ----------------
    int w = t >> 6;
    int l15 = lane & 15;
    int q8 = (lane >> 4) * 8;
    int split = blockIdx.x & 15;
    int b0 = (blockIdx.x >> 4) * 16;
    int k0 = split * 1024;
    f32x4 a00 = {}, a01 = {};
    const unsigned short* x0 = rnb + (size_t)(b0 + l15) * 16384 + k0 + q8;
    const unsigned short* w0 = WgT + (size_t)(w * 32 + l15) * 16384 + k0 + q8;
    const unsigned short* w1 = w0 + (size_t)16 * 16384;
#pragma unroll 8
    for (int ks = 0; ks < 32; ++ks) {
        int kk = ks * 32;
        bf16x8 af0 = *(const bf16x8*)(x0 + kk);
        bf16x8 bf0 = *(const bf16x8*)(w0 + kk);
        bf16x8 bf1 = *(const bf16x8*)(w1 + kk);
        a00 = __builtin_amdgcn_mfma_f32_16x16x32_bf16(af0, bf0, a00, 0, 0, 0);
        a01 = __builtin_amdgcn_mfma_f32_16x16x32_bf16(af0, bf1, a01, 0, 0, 0);
    }
    int row = (lane >> 4) * 4;
    size_t base = (size_t)split * (B_ * 128);
    float* g = Gpart + base + (size_t)(b0 + row) * 128 + w * 32 + l15;
#pragma unroll
    for (int r = 0; r < 4; ++r) {
        g[(size_t)r * 128] = a00[r];
        g[(size_t)r * 128 + 16] = a01[r];
    }
}

// ---------------------------------------------------------------------------
// per-step small: Ab = sum(Gpart) + rho*AAH*(z-u);  qb = bf16(rho*(z-u) - S^-1*Ab)
__global__ __launch_bounds__(256) void k_small12(const float* Gpart, const float* AAHT,
                                                 const float* Wt, const float* zin,
                                                 const float* uin, const float* lr,
                                                 unsigned short* qb) {
    __shared__ float2 AbS[4][64];
    int t = threadIdx.x;
    int m = t & 63;
    int w = __builtin_amdgcn_readfirstlane(t >> 6);
    int b = blockIdx.x * 4 + w;
    float rho = expf(lr[0]);
    float abR = 0.f, abI = 0.f;
    for (int k = 0; k < 64; ++k) {
        float wr = zin[(b * 2 + 0) * 64 + k] - uin[(b * 2 + 0) * 64 + k];
        float wi = zin[(b * 2 + 1) * 64 + k] - uin[(b * 2 + 1) * 64 + k];
        float2 h = *(const float2*)(AAHT + ((size_t)k * 64 + m) * 2);  // AAH[m][k]
        abR += wr * h.x - wi * h.y;
        abI += wi * h.x + wr * h.y;
    }
    float gR = 0.f, gI = 0.f;
#pragma unroll
    for (int s = 0; s < NSG; ++s) {
        gR += Gpart[(size_t)s * 131072 + (size_t)b * 128 + m];
        gI += Gpart[(size_t)s * 131072 + (size_t)b * 128 + 64 + m];
    }
    abR = gR + rho * abR;
    abI = gI + rho * abI;
    AbS[w][m] = make_float2(abR, abI);
    __syncthreads();
    float tR = 0.f, tI = 0.f;
    for (int k = 0; k < 64; ++k) {
        float2 Wv = *(const float2*)(Wt + ((size_t)k * 64 + m) * 2);   // W[m][k]
        float2 ab = AbS[w][k];
        tR += ab.x * Wv.x - ab.y * Wv.y;
        tI += ab.y * Wv.x + ab.x * Wv.y;
    }
    float wr_m = zin[(b * 2 + 0) * 64 + m] - uin[(b * 2 + 0) * 64 + m];
    float wi_m = zin[(b * 2 + 1) * 64 + m] - uin[(b * 2 + 1) * 64 + m];
    qb[(size_t)b * 128 + m] = f2b(rho * wr_m - tR);
    qb[(size_t)b * 128 + 64 + m] = f2b(rho * wi_m - tI);
}

// ---------------------------------------------------------------------------
// k_H23: fused x-update + Ax partials; last step also writes fp32 out (real)
// and zeros the imag rows (absorbs k_zero_imag). rn read as bf16 (rnb).
__global__ __launch_bounds__(256, 3) void k_H23(const unsigned short* qb, const unsigned short* ATb,
                                                const unsigned short* rnb, const unsigned short* Abf,
                                                float* out, float* Axpart, int last) {
    __shared__ __align__(16) char lds_buf[4 * 8448];
    int t = threadIdx.x;
    int lane = t & 63;
    int w = t >> 6;
    int l15 = lane & 15;
    int q8 = (lane >> 4) * 8;
    int row = (lane >> 4) * 4;
    int slab = blockIdx.x;
    int b0 = blockIdx.y * 16;
    int n0 = slab * 1024 + w * 256;
    short* xs = (short*)(lds_buf + w * 8448);      // [16][264] bf16 (row stride 528B)
    float* rs = (float*)(lds_buf + w * 8448);      // [16][132] fp32 alias (same wave only)

    // ---- phase 1
    bf16x8 a[4];
    const unsigned short* qrow = qb + (size_t)(b0 + l15) * 128 + q8;
#pragma unroll
    for (int ks = 0; ks < 4; ++ks) a[ks] = *(const bf16x8*)(qrow + ks * 32);
#pragma unroll 2
    for (int nt = 0; nt < 16; ++nt) {
        f32x4 acc = {};
        const unsigned short* bbase = ATb + (size_t)(n0 + nt * 16 + l15) * 128 + q8;
#pragma unroll
        for (int ks = 0; ks < 4; ++ks) {
            bf16x8 bf = *(const bf16x8*)(bbase + ks * 32);
            acc = __builtin_amdgcn_mfma_f32_16x16x32_bf16(a[ks], bf, acc, 0, 0, 0);
        }
        int ncol = n0 + nt * 16 + l15;
        int nloc = nt * 16 + l15;
#pragma unroll
        for (int r = 0; r < 4; ++r) {
            size_t ridx = (size_t)(b0 + row + r) * 16384 + ncol;   // real row of rn/out
            float v = fmaxf(acc[r] + b2f(rnb[ridx]), 0.f);
            if (last) out[ridx] = v;
            xs[(row + r) * 264 + nloc] = (short)f2b(v);
        }
    }
    // ---- phase 2 (wave-private x-stage: lgkmcnt orders RAW)
    f32x4 acc8[8] = {};
#pragma unroll
    for (int ks = 0; ks < 8; ++ks) {
        bf16x8 xf = *(const bf16x8*)(xs + l15 * 264 + ks * 32 + q8);
#pragma unroll
        for (int ot = 0; ot < 8; ++ot) {
            const unsigned short* bp = Abf + (size_t)(ot * 16 + l15) * 8192 + n0 + ks * 32 + q8;
            acc8[ot] = __builtin_amdgcn_mfma_f32_16x16x32_bf16(xf, *(const bf16x8*)bp, acc8[ot], 0, 0, 0);
        }
    }
    // ---- phase 3
    __syncthreads();
#pragma unroll
    for (int ot = 0; ot < 8; ++ot)
#pragma unroll
        for (int r = 0; r < 4; ++r)
            rs[(row + r) * 132 + ot * 16 + l15] = acc8[ot][r];
    __syncthreads();
#pragma unroll
    for (int e = t; e < 2048; e += 256) {
        int b = e >> 7, o = e & 127;
        float sAx = 0.f;
#pragma unroll
        for (int ww = 0; ww < 4; ++ww)
            sAx += ((const float*)(lds_buf + ww * 8448))[b * 132 + o];
        Axpart[(size_t)slab * 131072 + (size_t)(b0 + b) * 128 + o] = sAx;
    }
    // ---- zero imag rows of out (absorbed k_zero_imag)
    if (last) {
        float4 z4 = make_float4(0.f, 0.f, 0.f, 0.f);
        for (int e = t; e < 4096; e += 256) {
            int bb = e >> 8, nq = e & 255;
            *(float4*)(out + ((size_t)(b0 + bb) * 2 + 1) * N_ + slab * 1024 + nq * 4) = z4;
        }
    }
}

// ---------------------------------------------------------------------------
// per-step epilogue
__global__ __launch_bounds__(128) void k_small3(const float* Axpart, const float* uin,
                                                const float* y, const float* le,
                                                float* z, float* u, float* uout, int last) {
    __shared__ float red[2];
    int b = blockIdx.x, t = threadIdx.x;
    size_t idx = (size_t)b * 128 + t;
    float ax = 0.f;
#pragma unroll
    for (int s = 0; s < NS3; ++s) ax += Axpart[(size_t)s * 131072 + idx];
    float uo = uin[idx], yv = y[idx];
    float v = ax + uo - yv;
    float sq = v * v;
    for (int off = 32; off > 0; off >>= 1) sq += __shfl_down(sq, off, 64);
    if ((t & 63) == 0) red[t >> 6] = sq;
    __syncthreads();
    float tot = red[0] + red[1];
    float eps = expf(le[0]);
    float scale = fminf(1.f, eps / (sqrtf(tot) + 1e-12f));
    float zv = yv + v * scale;
    float un = uo + ax - zv;
    z[idx] = zv;
    u[idx] = un;
    if (last) uout[idx] = un;
}

// ---------------------------------------------------------------------------
extern "C" void kernel_launch(void* const* d_in, const int* in_sizes, int n_in,
                              void* d_out, int out_size, void* d_ws, size_t ws_size,
                              hipStream_t stream) {
    const float* rn  = (const float*)d_in[0];   // (B,2,N)
    const float* y   = (const float*)d_in[1];   // (B,2,M)
    const float* uin = (const float*)d_in[2];   // (B,2,M)
    const float* A   = (const float*)d_in[3];   // (2,M,N)
    const float* lr  = (const float*)d_in[4];   // log_rho
    const float* le  = (const float*)d_in[5];   // log_epsilon

    float* out = (float*)d_out;
    float* ws  = (float*)d_ws;

    float* Gpart  = ws;                             // 16*131072 = 2,097,152 f
    float* Axpart = Gpart + (size_t)NSG * 131072;   //  8*131072 = 1,048,576 f
    float* S      = Axpart + (size_t)NS3 * 131072;  // 8192
    float* AAHT   = S + 8192;                       // 8192
    float* Wt     = AAHT + 8192;                    // 8192
    float* z      = Wt + 8192;                      // 131072
    float* u      = z + 131072;                     // 131072
    unsigned short* qb  = (unsigned short*)(u + 131072);  // 131,072 us
    unsigned short* rnb = qb + 131072;              // B*2*N  = 16,777,216 us
    unsigned short* WgT = rnb + (size_t)B_ * 16384; // 128*16384 = 2,097,152 us
    unsigned short* Abf = WgT + 2097152;            // 2*64*8192 = 1,048,576 us
    unsigned short* ATb = Abf + 1048576;            // 8192*128  = 1,048,576 us
    float* uout = out + (size_t)B_ * 2 * N_;

    k_prep<<<128, 256, 0, stream>>>(A, Abf, WgT, ATb);
    k_cvt<<<8192, 256, 0, stream>>>(rn, rnb);
    k_Sbuild<<<2080, 256, 0, stream>>>(A, lr, S, AAHT);
    k_Ginv<<<1025, 256, 0, stream>>>(rnb, WgT, Gpart, S, Wt);

    for (int step = 0; step < 3; ++step) {
        const float* zp = (step == 0) ? y   : z;
        const float* up = (step == 0) ? uin : u;
        int last = (step == 2) ? 1 : 0;
        k_small12<<<256, 256, 0, stream>>>(Gpart, AAHT, Wt, zp, up, lr, qb);
        k_H23<<<dim3(NS3, 64), 256, 0, stream>>>(qb, ATb, rnb, Abf, out, Axpart, last);
        k_small3<<<B_, 128, 0, stream>>>(Axpart, up, y, le, z, u, uout, last);
    }
}